// Round 3
// baseline (40258.731 us; speedup 1.0000x reference)
//
#include <hip/hip_runtime.h>
#include <cstdint>
#include <cstddef>

// Problem constants (match reference)
#define N_ITEMS 16384
#define D_STATE 2048
#define D_SEM   1024
#define S_SLOTS 4096
#define DTHRESH 2.0f

#define B_ITEMS 256              // sequential-scan block size
#define CHUNK_BLKS 16            // content-GEMM chunking (16 MB buffer)
#define CHUNK_ITEMS (B_ITEMS * CHUNK_BLKS)  // 4096

typedef unsigned long long u64;
typedef unsigned int u32;

// ---------------------------------------------------------------------------
// Content GEMM: C[i,j] = sum_d A[i,d]*W[j,d] + b[j].  64x64 tile, K=2048.
// ---------------------------------------------------------------------------
__global__ __launch_bounds__(256)
void gemm_kernel(const float* __restrict__ A, const float* __restrict__ W,
                 const float* __restrict__ bias, float* __restrict__ C) {
  __shared__ float As[16][68];
  __shared__ float Bs[16][68];
  const int t = threadIdx.x;
  const int ty = t >> 4, tx = t & 15;
  const int i0 = blockIdx.x * 64, j0 = blockIdx.y * 64;
  const int lrow = t >> 2, lcol = (t & 3) << 2;
  float acc[4][4] = {{0.f}};
  const float* ap = A + (size_t)(i0 + lrow) * D_STATE + lcol;
  const float* wp = W + (size_t)(j0 + lrow) * D_STATE + lcol;
  for (int k0 = 0; k0 < D_STATE; k0 += 16) {
    float4 av = *(const float4*)(ap + k0);
    float4 wv = *(const float4*)(wp + k0);
    __syncthreads();
    As[lcol + 0][lrow] = av.x; As[lcol + 1][lrow] = av.y;
    As[lcol + 2][lrow] = av.z; As[lcol + 3][lrow] = av.w;
    Bs[lcol + 0][lrow] = wv.x; Bs[lcol + 1][lrow] = wv.y;
    Bs[lcol + 2][lrow] = wv.z; Bs[lcol + 3][lrow] = wv.w;
    __syncthreads();
#pragma unroll
    for (int kk = 0; kk < 16; kk++) {
      float a[4], b[4];
#pragma unroll
      for (int y = 0; y < 4; y++) a[y] = As[kk][ty * 4 + y];
#pragma unroll
      for (int x = 0; x < 4; x++) b[x] = Bs[kk][tx * 4 + x];
#pragma unroll
      for (int y = 0; y < 4; y++)
#pragma unroll
        for (int x = 0; x < 4; x++) acc[y][x] = fmaf(a[y], b[x], acc[y][x]);
    }
  }
#pragma unroll
  for (int y = 0; y < 4; y++)
#pragma unroll
    for (int x = 0; x < 4; x++) {
      const int col = j0 + tx * 4 + x;
      C[(size_t)(i0 + ty * 4 + y) * D_SEM + col] = acc[y][x] + bias[col];
    }
}

// ---------------------------------------------------------------------------
// Per-chunk block-diagonal Gram: G[z][i][j] = c_i . c_j within block z.
// ---------------------------------------------------------------------------
__global__ __launch_bounds__(256)
void gram_kernel(const float* __restrict__ Cc, float* __restrict__ G) {
  const int z = blockIdx.z;
  const float* A = Cc + (size_t)z * B_ITEMS * D_SEM;
  __shared__ float As[16][68];
  __shared__ float Bs[16][68];
  const int t = threadIdx.x;
  const int ty = t >> 4, tx = t & 15;
  const int i0 = blockIdx.x * 64, j0 = blockIdx.y * 64;
  const int lrow = t >> 2, lcol = (t & 3) << 2;
  float acc[4][4] = {{0.f}};
  const float* ap = A + (size_t)(i0 + lrow) * D_SEM + lcol;
  const float* wp = A + (size_t)(j0 + lrow) * D_SEM + lcol;
  for (int k0 = 0; k0 < D_SEM; k0 += 16) {
    float4 av = *(const float4*)(ap + k0);
    float4 wv = *(const float4*)(wp + k0);
    __syncthreads();
    As[lcol + 0][lrow] = av.x; As[lcol + 1][lrow] = av.y;
    As[lcol + 2][lrow] = av.z; As[lcol + 3][lrow] = av.w;
    Bs[lcol + 0][lrow] = wv.x; Bs[lcol + 1][lrow] = wv.y;
    Bs[lcol + 2][lrow] = wv.z; Bs[lcol + 3][lrow] = wv.w;
    __syncthreads();
#pragma unroll
    for (int kk = 0; kk < 16; kk++) {
      float a[4], b[4];
#pragma unroll
      for (int y = 0; y < 4; y++) a[y] = As[kk][ty * 4 + y];
#pragma unroll
      for (int x = 0; x < 4; x++) b[x] = Bs[kk][tx * 4 + x];
#pragma unroll
      for (int y = 0; y < 4; y++)
#pragma unroll
        for (int x = 0; x < 4; x++) acc[y][x] = fmaf(a[y], b[x], acc[y][x]);
    }
  }
  float* Gz = G + (size_t)z * B_ITEMS * B_ITEMS;
#pragma unroll
  for (int y = 0; y < 4; y++)
#pragma unroll
    for (int x = 0; x < 4; x++)
      Gz[(size_t)(i0 + ty * 4 + y) * B_ITEMS + j0 + tx * 4 + x] = acc[y][x];
}

// ---------------------------------------------------------------------------
// Per-block pre-distance: Q[i][s] = ||t_s||^2 - 2 * c_i . t_s  (s < limit).
// ---------------------------------------------------------------------------
__global__ __launch_bounds__(256)
void pgemm_kernel(const float* __restrict__ A,   // content block 256 x 1024
                  const float* __restrict__ T,   // traces (= out) 4096 x 1024
                  const float* __restrict__ n_g, // ||t_s||^2
                  float* __restrict__ Q,
                  const int* __restrict__ state) {
  const int limit = min(state[0] + B_ITEMS, S_SLOTS);
  const int j0 = blockIdx.y * 64;
  if (j0 >= limit) return;
  __shared__ float As[16][68];
  __shared__ float Bs[16][68];
  const int t = threadIdx.x;
  const int ty = t >> 4, tx = t & 15;
  const int i0 = blockIdx.x * 64;
  const int lrow = t >> 2, lcol = (t & 3) << 2;
  float acc[4][4] = {{0.f}};
  const float* ap = A + (size_t)(i0 + lrow) * D_SEM + lcol;
  const float* wp = T + (size_t)(j0 + lrow) * D_SEM + lcol;
  for (int k0 = 0; k0 < D_SEM; k0 += 16) {
    float4 av = *(const float4*)(ap + k0);
    float4 wv = *(const float4*)(wp + k0);
    __syncthreads();
    As[lcol + 0][lrow] = av.x; As[lcol + 1][lrow] = av.y;
    As[lcol + 2][lrow] = av.z; As[lcol + 3][lrow] = av.w;
    Bs[lcol + 0][lrow] = wv.x; Bs[lcol + 1][lrow] = wv.y;
    Bs[lcol + 2][lrow] = wv.z; Bs[lcol + 3][lrow] = wv.w;
    __syncthreads();
#pragma unroll
    for (int kk = 0; kk < 16; kk++) {
      float a[4], b[4];
#pragma unroll
      for (int y = 0; y < 4; y++) a[y] = As[kk][ty * 4 + y];
#pragma unroll
      for (int x = 0; x < 4; x++) b[x] = Bs[kk][tx * 4 + x];
#pragma unroll
      for (int y = 0; y < 4; y++)
#pragma unroll
        for (int x = 0; x < 4; x++) acc[y][x] = fmaf(a[y], b[x], acc[y][x]);
    }
  }
#pragma unroll
  for (int y = 0; y < 4; y++)
#pragma unroll
    for (int x = 0; x < 4; x++) {
      const int col = j0 + tx * 4 + x;
      Q[(size_t)(i0 + ty * 4 + y) * S_SLOTS + col] = n_g[col] - 2.0f * acc[y][x];
    }
}

// ---------------------------------------------------------------------------
// init: copy traces0 -> out (working traces), n_g[s] = ||t_s||^2, reset state.
// ---------------------------------------------------------------------------
__global__ __launch_bounds__(256)
void init_kernel(const float* __restrict__ traces0, float* __restrict__ out,
                 float* __restrict__ n_g, int* __restrict__ state) {
  __shared__ float wsum[4];
  const int s = blockIdx.x, t = threadIdx.x;
  const int lane = t & 63, wave = t >> 6;
  float4 v = *(const float4*)(traces0 + (size_t)s * D_SEM + 4 * t);
  *(float4*)(out + (size_t)s * D_SEM + 4 * t) = v;
  float nn = v.x * v.x + v.y * v.y + v.z * v.z + v.w * v.w;
#pragma unroll
  for (int o = 32; o; o >>= 1) nn += __shfl_down(nn, o, 64);
  if (lane == 0) wsum[wave] = nn;
  __syncthreads();
  if (t == 0) n_g[s] = wsum[0] + wsum[1] + wsum[2] + wsum[3];
  if (s == 0 && t == 0) { state[0] = 0; state[1] = 0; }
}

// ---------------------------------------------------------------------------
// Sequential scan over one block of 256 items. SINGLE workgroup, 256 thr.
// Thread t holds Q-row slice for slots 16t..16t+15 in registers. 2 barriers
// per step; decision computed redundantly by ALL threads from LDS broadcast
// reads; num/ptr tracked in registers; all decision-independent loads
// prefetched at step start. Arithmetic identical to the round-2 kernel.
// ---------------------------------------------------------------------------
__global__ __launch_bounds__(256)
void scan_kernel(float* __restrict__ Q, const float* __restrict__ Gb,
                 const float* __restrict__ rewards, const float* __restrict__ n_g,
                 int* __restrict__ state, u64* __restrict__ decs) {
  __shared__ float n_l[S_SLOTS];     // ||t_s||^2, tracked incrementally
  __shared__ float rew[B_ITEMS];
  __shared__ float gdiag[B_ITEMS];   // ||c_i||^2
  __shared__ u64 partials[4];
  __shared__ float sh_gnext;         // G[i][i+1] staged by thread i+1
  __shared__ u32 dslot[B_ITEMS];
  __shared__ float dlr[B_ITEMS];
  __shared__ int sh_state[2];

  const int t = threadIdx.x;          // 0..255
  const int lane = t & 63, wave = t >> 6;

  for (int s = t; s < S_SLOTS; s += 256) n_l[s] = n_g[s];
  rew[t] = rewards[t];
  gdiag[t] = Gb[(size_t)t * B_ITEMS + t];
  if (t == 0) { sh_state[0] = state[0]; sh_state[1] = state[1]; }
  __syncthreads();

  int num = sh_state[0], ptr = sh_state[1];
  const int limit = min(num + B_ITEMS, S_SLOTS);
  const int s0 = t << 4;
  const bool active = s0 < limit;

  float4 c[4];
  if (active) {
    c[0] = *(const float4*)(Q + s0 + 0);
    c[1] = *(const float4*)(Q + s0 + 4);
    c[2] = *(const float4*)(Q + s0 + 8);
    c[3] = *(const float4*)(Q + s0 + 12);
  }
  float gv = Gb[t];                   // Gb row 0
  int slot_prev = -1; float nnew_prev = 0.f;

  for (int i = 0; i < B_ITEMS; i++) {
    // ---- step start: all decision-independent work ----
    float4 cn[4]; float gvnext = 0.f;
    if (i + 1 < B_ITEMS) {
      if (active) {
        const float* qrow = Q + (size_t)(i + 1) * S_SLOTS + s0;
        cn[0] = *(const float4*)(qrow + 0);
        cn[1] = *(const float4*)(qrow + 4);
        cn[2] = *(const float4*)(qrow + 8);
        cn[3] = *(const float4*)(qrow + 12);
      }
      gvnext = Gb[(size_t)(i + 1) * B_ITEMS + t];
    }
    if (t == i + 1) sh_gnext = gv;                  // G[i][i+1]
    if (t == 0 && slot_prev >= 0) n_l[slot_prev] = nnew_prev;  // deferred write

    // ---- phase A: 16-slot compare + wave argmin ----
    const float gi = gdiag[i];
    u64 best = ~0ull;
    if (active) {
#define KEYC(vec, comp, idx) { const int ss = s0 + idx; \
    if (ss < num) { const float d2 = fmaxf(vec.comp + gi, 0.f); \
      const u64 key = ((u64)__float_as_uint(d2) << 32) | (u32)ss; \
      if (key < best) best = key; } }
      KEYC(c[0], x, 0)  KEYC(c[0], y, 1)  KEYC(c[0], z, 2)  KEYC(c[0], w, 3)
      KEYC(c[1], x, 4)  KEYC(c[1], y, 5)  KEYC(c[1], z, 6)  KEYC(c[1], w, 7)
      KEYC(c[2], x, 8)  KEYC(c[2], y, 9)  KEYC(c[2], z, 10) KEYC(c[2], w, 11)
      KEYC(c[3], x, 12) KEYC(c[3], y, 13) KEYC(c[3], z, 14) KEYC(c[3], w, 15)
#undef KEYC
    }
#pragma unroll
    for (int o = 32; o; o >>= 1) {
      const u64 v = __shfl_down(best, o, 64);
      if (v < best) best = v;
    }
    if (lane == 0) partials[wave] = best;
    __syncthreads();

    // ---- phase B: ALL threads compute the decision redundantly ----
    u64 bk = partials[0];
    if (partials[1] < bk) bk = partials[1];
    if (partials[2] < bk) bk = partials[2];
    if (partials[3] < bk) bk = partials[3];
    const float d2b = __uint_as_float((u32)(bk >> 32));
    const int nslot = (int)(u32)bk;
    const bool upd = (num > 0) && (sqrtf(d2b) < DTHRESH);
    const float lr = __fmul_rn(0.01f, __fadd_rn(1.0f, fabsf(rew[i])));
    const int slot = upd ? nslot : ptr;
    const float n_old = n_l[slot];                  // LDS broadcast
    float n_new;
    if (upd) {
      const float omr = 1.0f - lr;
      const float pcur = 0.5f * (n_old + gi - d2b);
      n_new = omr * omr * n_old + 2.0f * lr * omr * pcur + lr * lr * gi;
    } else {
      n_new = gi;
      num = min(num + 1, S_SLOTS);
      ptr = (ptr + 1) & (S_SLOTS - 1);
    }
    if (t == 0) {
      dslot[i] = (u32)slot | (upd ? 0x80000000u : 0u);
      dlr[i] = lr;
    }

    // ---- phase C: apply mutation to future rows ----
    const float omr = 1.0f - lr;
    if (i + 1 < B_ITEMS) {
      if (t == (slot >> 4)) {       // register fixup for row i+1
        const float gnext = sh_gnext;
        const int kq = (slot >> 2) & 3, kc = slot & 3;
#pragma unroll
        for (int q = 0; q < 4; q++) {
          if (q == kq) {
            float4 vv = cn[q];
            const float q_old = kc == 0 ? vv.x : kc == 1 ? vv.y : kc == 2 ? vv.z : vv.w;
            const float p_old = 0.5f * (n_old - q_old);
            const float p_new = upd ? (omr * p_old + lr * gnext) : gnext;
            const float q_new = n_new - 2.0f * p_new;
            if (kc == 0) vv.x = q_new; else if (kc == 1) vv.y = q_new;
            else if (kc == 2) vv.z = q_new; else vv.w = q_new;
            cn[q] = vv;
          }
        }
      }
      if (t > i + 1) {              // L2 RMW for rows i+2..255
        float* qp = Q + (size_t)t * S_SLOTS + slot;
        float p_new;
        if (upd) {
          const float p_old = 0.5f * (n_old - *qp);
          p_new = omr * p_old + lr * gv;
        } else {
          p_new = gv;
        }
        *qp = n_new - 2.0f * p_new;
      }
    }
    slot_prev = slot; nnew_prev = n_new;
    __syncthreads();                // drains RMW stores before next prefetch use

    if (active && i + 1 < B_ITEMS) {
      c[0] = cn[0]; c[1] = cn[1]; c[2] = cn[2]; c[3] = cn[3];
    }
    gv = gvnext;
  }

  if (t == 0) { state[0] = num; state[1] = ptr; }
  decs[t] = ((u64)__float_as_uint(dlr[t]) << 32) | (u64)dslot[t];
}

// ---------------------------------------------------------------------------
// apply: materialize the block's trace mutations. WG j owns slot_j iff step j
// is the LAST step touching it. Composition: t = alpha*t_snap + sum beta_j c_j.
// ---------------------------------------------------------------------------
__global__ __launch_bounds__(256)
void apply_kernel(const float* __restrict__ content,  // block 256 x 1024
                  const u64* __restrict__ decs,       // 256 decisions
                  float* __restrict__ traces,         // = out
                  float* __restrict__ n_g) {
  __shared__ u32 aslot[B_ITEMS];
  __shared__ float alr[B_ITEMS];
  __shared__ float betas[B_ITEMS];
  __shared__ int notowner;
  __shared__ float wsum[4];
  const int t = threadIdx.x, j = blockIdx.x;
  const int lane = t & 63, wave = t >> 6;
  const u64 d = decs[t];
  aslot[t] = (u32)(d & 0xFFFFFFFFull);
  alr[t] = __uint_as_float((u32)(d >> 32));
  if (t == 0) notowner = 0;
  __syncthreads();
  const u32 myslot = aslot[j] & 0x7FFFFFFFu;
  if (t > j && (aslot[t] & 0x7FFFFFFFu) == myslot) notowner = 1;
  __syncthreads();
  if (notowner) return;

  float alpha = 1.f, beta = 0.f;
  for (int k = 0; k < B_ITEMS; k++) {
    const u32 a = aslot[k];
    if ((a & 0x7FFFFFFFu) == myslot) {
      const float lr = alr[k];
      if (a & 0x80000000u) {           // update
        const float om = 1.f - lr;
        alpha *= om; beta *= om;
        if (t == k) beta += lr;
      } else {                         // insert
        alpha = 0.f; beta = (t == k) ? 1.f : 0.f;
      }
    }
  }
  betas[t] = beta;
  __syncthreads();

  float4 v = *(const float4*)(traces + (size_t)myslot * D_SEM + 4 * t);
  v.x *= alpha; v.y *= alpha; v.z *= alpha; v.w *= alpha;
  for (int k = 0; k < B_ITEMS; k++) {
    if ((aslot[k] & 0x7FFFFFFFu) == myslot) {
      const float bk = betas[k];
      const float4 c = *(const float4*)(content + (size_t)k * D_SEM + 4 * t);
      v.x = fmaf(bk, c.x, v.x); v.y = fmaf(bk, c.y, v.y);
      v.z = fmaf(bk, c.z, v.z); v.w = fmaf(bk, c.w, v.w);
    }
  }
  *(float4*)(traces + (size_t)myslot * D_SEM + 4 * t) = v;
  float nn = v.x * v.x + v.y * v.y + v.z * v.z + v.w * v.w;
#pragma unroll
  for (int o = 32; o; o >>= 1) nn += __shfl_down(nn, o, 64);
  if (lane == 0) wsum[wave] = nn;
  __syncthreads();
  if (t == 0) n_g[myslot] = wsum[0] + wsum[1] + wsum[2] + wsum[3];
}

// ---------------------------------------------------------------------------
// finalize: parallel strengths replay. Pass 1: last insert index per slot
// (LDS atomicMax). Pass 2: count updates after the last insert (LDS atomicAdd).
// ---------------------------------------------------------------------------
__global__ __launch_bounds__(256)
void finalize_kernel(const float* __restrict__ strengths0,
                     const u64* __restrict__ decs,
                     const int* __restrict__ state, float* __restrict__ out) {
  __shared__ float str[S_SLOTS];
  __shared__ int lastins[S_SLOTS];
  __shared__ float wsum[4];
  const int t = threadIdx.x, lane = t & 63, wave = t >> 6;
  for (int s = t; s < S_SLOTS; s += 256) lastins[s] = -1;
  __syncthreads();
  for (int k = t; k < N_ITEMS; k += 256) {
    const u32 d = (u32)(decs[k] & 0xFFFFFFFFull);
    if (!(d & 0x80000000u)) atomicMax(&lastins[d & 0x7FFFFFFFu], k);
  }
  __syncthreads();
  for (int s = t; s < S_SLOTS; s += 256)
    str[s] = (lastins[s] >= 0) ? 1.f : strengths0[s];
  __syncthreads();
  for (int k = t; k < N_ITEMS; k += 256) {
    const u32 d = (u32)(decs[k] & 0xFFFFFFFFull);
    if (d & 0x80000000u) {
      const int slot = (int)(d & 0x7FFFFFFFu);
      if (k > lastins[slot]) atomicAdd(&str[slot], 1.f);
    }
  }
  __syncthreads();

  const int num = state[0];
  float* outs = out + (size_t)S_SLOTS * D_SEM;
  float lsum = 0.f;
  for (int s = t; s < S_SLOTS; s += 256) {
    const float v = str[s];
    outs[s] = v;
    if (s < num) lsum += v;
  }
#pragma unroll
  for (int o = 32; o; o >>= 1) lsum += __shfl_down(lsum, o, 64);
  if (lane == 0) wsum[wave] = lsum;
  __syncthreads();
  if (t == 0) {
    const float total = wsum[0] + wsum[1] + wsum[2] + wsum[3];
    float denom = (float)num;
    if (denom < 1.f) denom = 1.f;
    outs[S_SLOTS + 0] = (float)num;
    outs[S_SLOTS + 1] = (float)N_ITEMS;
    outs[S_SLOTS + 2] = (num > 0) ? (total / denom) : 0.f;
  }
}

// ---------------------------------------------------------------------------
extern "C" void kernel_launch(void* const* d_in, const int* in_sizes, int n_in,
                              void* d_out, int out_size, void* d_ws, size_t ws_size,
                              hipStream_t stream) {
  const float* states  = (const float*)d_in[0];
  const float* rewards = (const float*)d_in[1];
  const float* W       = (const float*)d_in[2];
  const float* bias    = (const float*)d_in[3];
  const float* traces0 = (const float*)d_in[4];
  const float* str0    = (const float*)d_in[5];
  float* out = (float*)d_out;   // traces live here (working + final)

  // ws layout (~24.5 MB): content chunk 16MB | Q 4MB | Gram 4MB | n_g | decs | state
  char* p = (char*)d_ws;
  float* cbuf = (float*)p;                 p += (size_t)CHUNK_ITEMS * D_SEM * 4;
  float* Q    = (float*)p;                 p += (size_t)B_ITEMS * S_SLOTS * 4;
  float* Gb   = (float*)p;                 p += (size_t)CHUNK_BLKS * B_ITEMS * B_ITEMS * 4;
  float* n_g  = (float*)p;                 p += (size_t)S_SLOTS * 4;
  u64*   decs = (u64*)p;                   p += (size_t)N_ITEMS * 8;
  int*   state = (int*)p;

  init_kernel<<<S_SLOTS, 256, 0, stream>>>(traces0, out, n_g, state);

  for (int c = 0; c < N_ITEMS / CHUNK_ITEMS; c++) {
    gemm_kernel<<<dim3(CHUNK_ITEMS / 64, D_SEM / 64), 256, 0, stream>>>(
        states + (size_t)c * CHUNK_ITEMS * D_STATE, W, bias, cbuf);
    gram_kernel<<<dim3(4, 4, CHUNK_BLKS), 256, 0, stream>>>(cbuf, Gb);
    for (int bb = 0; bb < CHUNK_BLKS; bb++) {
      const int b = c * CHUNK_BLKS + bb;
      const float* cblk = cbuf + (size_t)bb * B_ITEMS * D_SEM;
      const float* Gblk = Gb + (size_t)bb * B_ITEMS * B_ITEMS;
      pgemm_kernel<<<dim3(4, S_SLOTS / 64), 256, 0, stream>>>(cblk, out, n_g, Q, state);
      scan_kernel<<<1, 256, 0, stream>>>(Q, Gblk, rewards + (size_t)b * B_ITEMS,
                                         n_g, state, decs + (size_t)b * B_ITEMS);
      apply_kernel<<<B_ITEMS, 256, 0, stream>>>(cblk, decs + (size_t)b * B_ITEMS,
                                                out, n_g);
    }
  }
  finalize_kernel<<<1, 256, 0, stream>>>(str0, decs, state, out);
}

// Round 4
// 40053.220 us; speedup vs baseline: 1.0051x; 1.0051x over previous
//
#include <hip/hip_runtime.h>
#include <cstdint>
#include <cstddef>

// Problem constants (match reference)
#define N_ITEMS 16384
#define D_STATE 2048
#define D_SEM   1024
#define S_SLOTS 4096
#define DTHRESH 2.0f

#define B_ITEMS 256              // sequential-scan block size
#define CHUNK_BLKS 16            // content-GEMM chunking (16 MB buffer)
#define CHUNK_ITEMS (B_ITEMS * CHUNK_BLKS)  // 4096
#define SCAN_GRID 256            // 1 real WG + 255 clock-keeper fillers

typedef unsigned long long u64;
typedef unsigned int u32;

// ---------------------------------------------------------------------------
// Content GEMM: C[i,j] = sum_d A[i,d]*W[j,d] + b[j].  64x64 tile, K=2048.
// ---------------------------------------------------------------------------
__global__ __launch_bounds__(256)
void gemm_kernel(const float* __restrict__ A, const float* __restrict__ W,
                 const float* __restrict__ bias, float* __restrict__ C) {
  __shared__ float As[16][68];
  __shared__ float Bs[16][68];
  const int t = threadIdx.x;
  const int ty = t >> 4, tx = t & 15;
  const int i0 = blockIdx.x * 64, j0 = blockIdx.y * 64;
  const int lrow = t >> 2, lcol = (t & 3) << 2;
  float acc[4][4] = {{0.f}};
  const float* ap = A + (size_t)(i0 + lrow) * D_STATE + lcol;
  const float* wp = W + (size_t)(j0 + lrow) * D_STATE + lcol;
  for (int k0 = 0; k0 < D_STATE; k0 += 16) {
    float4 av = *(const float4*)(ap + k0);
    float4 wv = *(const float4*)(wp + k0);
    __syncthreads();
    As[lcol + 0][lrow] = av.x; As[lcol + 1][lrow] = av.y;
    As[lcol + 2][lrow] = av.z; As[lcol + 3][lrow] = av.w;
    Bs[lcol + 0][lrow] = wv.x; Bs[lcol + 1][lrow] = wv.y;
    Bs[lcol + 2][lrow] = wv.z; Bs[lcol + 3][lrow] = wv.w;
    __syncthreads();
#pragma unroll
    for (int kk = 0; kk < 16; kk++) {
      float a[4], b[4];
#pragma unroll
      for (int y = 0; y < 4; y++) a[y] = As[kk][ty * 4 + y];
#pragma unroll
      for (int x = 0; x < 4; x++) b[x] = Bs[kk][tx * 4 + x];
#pragma unroll
      for (int y = 0; y < 4; y++)
#pragma unroll
        for (int x = 0; x < 4; x++) acc[y][x] = fmaf(a[y], b[x], acc[y][x]);
    }
  }
#pragma unroll
  for (int y = 0; y < 4; y++)
#pragma unroll
    for (int x = 0; x < 4; x++) {
      const int col = j0 + tx * 4 + x;
      C[(size_t)(i0 + ty * 4 + y) * D_SEM + col] = acc[y][x] + bias[col];
    }
}

// ---------------------------------------------------------------------------
// Per-chunk block-diagonal Gram: G[z][i][j] = c_i . c_j within block z.
// ---------------------------------------------------------------------------
__global__ __launch_bounds__(256)
void gram_kernel(const float* __restrict__ Cc, float* __restrict__ G) {
  const int z = blockIdx.z;
  const float* A = Cc + (size_t)z * B_ITEMS * D_SEM;
  __shared__ float As[16][68];
  __shared__ float Bs[16][68];
  const int t = threadIdx.x;
  const int ty = t >> 4, tx = t & 15;
  const int i0 = blockIdx.x * 64, j0 = blockIdx.y * 64;
  const int lrow = t >> 2, lcol = (t & 3) << 2;
  float acc[4][4] = {{0.f}};
  const float* ap = A + (size_t)(i0 + lrow) * D_SEM + lcol;
  const float* wp = A + (size_t)(j0 + lrow) * D_SEM + lcol;
  for (int k0 = 0; k0 < D_SEM; k0 += 16) {
    float4 av = *(const float4*)(ap + k0);
    float4 wv = *(const float4*)(wp + k0);
    __syncthreads();
    As[lcol + 0][lrow] = av.x; As[lcol + 1][lrow] = av.y;
    As[lcol + 2][lrow] = av.z; As[lcol + 3][lrow] = av.w;
    Bs[lcol + 0][lrow] = wv.x; Bs[lcol + 1][lrow] = wv.y;
    Bs[lcol + 2][lrow] = wv.z; Bs[lcol + 3][lrow] = wv.w;
    __syncthreads();
#pragma unroll
    for (int kk = 0; kk < 16; kk++) {
      float a[4], b[4];
#pragma unroll
      for (int y = 0; y < 4; y++) a[y] = As[kk][ty * 4 + y];
#pragma unroll
      for (int x = 0; x < 4; x++) b[x] = Bs[kk][tx * 4 + x];
#pragma unroll
      for (int y = 0; y < 4; y++)
#pragma unroll
        for (int x = 0; x < 4; x++) acc[y][x] = fmaf(a[y], b[x], acc[y][x]);
    }
  }
  float* Gz = G + (size_t)z * B_ITEMS * B_ITEMS;
#pragma unroll
  for (int y = 0; y < 4; y++)
#pragma unroll
    for (int x = 0; x < 4; x++)
      Gz[(size_t)(i0 + ty * 4 + y) * B_ITEMS + j0 + tx * 4 + x] = acc[y][x];
}

// ---------------------------------------------------------------------------
// Per-block pre-distance: Q[i][s] = ||t_s||^2 - 2 * c_i . t_s  (s < limit).
// Tile (0,0) also re-arms the scan filler flag (always runs, precedes scan).
// ---------------------------------------------------------------------------
__global__ __launch_bounds__(256)
void pgemm_kernel(const float* __restrict__ A,   // content block 256 x 1024
                  const float* __restrict__ T,   // traces (= out) 4096 x 1024
                  const float* __restrict__ n_g, // ||t_s||^2
                  float* __restrict__ Q,
                  const int* __restrict__ state,
                  int* __restrict__ scanflag) {
  if (blockIdx.x == 0 && blockIdx.y == 0 && threadIdx.x == 0)
    __hip_atomic_store(scanflag, 0, __ATOMIC_RELAXED, __HIP_MEMORY_SCOPE_AGENT);
  const int limit = min(state[0] + B_ITEMS, S_SLOTS);
  const int j0 = blockIdx.y * 64;
  if (j0 >= limit) return;
  __shared__ float As[16][68];
  __shared__ float Bs[16][68];
  const int t = threadIdx.x;
  const int ty = t >> 4, tx = t & 15;
  const int i0 = blockIdx.x * 64;
  const int lrow = t >> 2, lcol = (t & 3) << 2;
  float acc[4][4] = {{0.f}};
  const float* ap = A + (size_t)(i0 + lrow) * D_SEM + lcol;
  const float* wp = T + (size_t)(j0 + lrow) * D_SEM + lcol;
  for (int k0 = 0; k0 < D_SEM; k0 += 16) {
    float4 av = *(const float4*)(ap + k0);
    float4 wv = *(const float4*)(wp + k0);
    __syncthreads();
    As[lcol + 0][lrow] = av.x; As[lcol + 1][lrow] = av.y;
    As[lcol + 2][lrow] = av.z; As[lcol + 3][lrow] = av.w;
    Bs[lcol + 0][lrow] = wv.x; Bs[lcol + 1][lrow] = wv.y;
    Bs[lcol + 2][lrow] = wv.z; Bs[lcol + 3][lrow] = wv.w;
    __syncthreads();
#pragma unroll
    for (int kk = 0; kk < 16; kk++) {
      float a[4], b[4];
#pragma unroll
      for (int y = 0; y < 4; y++) a[y] = As[kk][ty * 4 + y];
#pragma unroll
      for (int x = 0; x < 4; x++) b[x] = Bs[kk][tx * 4 + x];
#pragma unroll
      for (int y = 0; y < 4; y++)
#pragma unroll
        for (int x = 0; x < 4; x++) acc[y][x] = fmaf(a[y], b[x], acc[y][x]);
    }
  }
#pragma unroll
  for (int y = 0; y < 4; y++)
#pragma unroll
    for (int x = 0; x < 4; x++) {
      const int col = j0 + tx * 4 + x;
      Q[(size_t)(i0 + ty * 4 + y) * S_SLOTS + col] = n_g[col] - 2.0f * acc[y][x];
    }
}

// ---------------------------------------------------------------------------
// init: copy traces0 -> out (working traces), n_g[s] = ||t_s||^2, reset state.
// ---------------------------------------------------------------------------
__global__ __launch_bounds__(256)
void init_kernel(const float* __restrict__ traces0, float* __restrict__ out,
                 float* __restrict__ n_g, int* __restrict__ state) {
  __shared__ float wsum[4];
  const int s = blockIdx.x, t = threadIdx.x;
  const int lane = t & 63, wave = t >> 6;
  float4 v = *(const float4*)(traces0 + (size_t)s * D_SEM + 4 * t);
  *(float4*)(out + (size_t)s * D_SEM + 4 * t) = v;
  float nn = v.x * v.x + v.y * v.y + v.z * v.z + v.w * v.w;
#pragma unroll
  for (int o = 32; o; o >>= 1) nn += __shfl_down(nn, o, 64);
  if (lane == 0) wsum[wave] = nn;
  __syncthreads();
  if (t == 0) n_g[s] = wsum[0] + wsum[1] + wsum[2] + wsum[3];
  if (s == 0 && t == 0) { state[0] = 0; state[1] = 0; }
}

// ---------------------------------------------------------------------------
// Sequential scan over one block of 256 items. WG 0 = real scan (arithmetic
// bit-identical to round 3). WGs 1..255 = clock-keeper fillers: dependent-FMA
// spin polling the done flag, so the power governor holds boost clocks while
// the lone scan WG runs. Fillers never gate WG0 -> no deadlock possible.
// ---------------------------------------------------------------------------
__global__ __launch_bounds__(256)
void scan_kernel(float* __restrict__ Q, const float* __restrict__ Gb,
                 const float* __restrict__ rewards, const float* __restrict__ n_g,
                 int* __restrict__ state, u64* __restrict__ decs,
                 int* __restrict__ scanflag) {
  if (blockIdx.x != 0) {           // ---- filler WG: keep the chip clocked ----
    float a = 1.0f + (float)threadIdx.x * 1e-7f;
    const float b = 1.0000001f;
    while (__hip_atomic_load(scanflag, __ATOMIC_RELAXED,
                             __HIP_MEMORY_SCOPE_AGENT) == 0) {
#pragma unroll
      for (int k = 0; k < 64; k++) a = fmaf(a, b, 1e-30f);
    }
    __asm__ volatile("" ::"v"(a));  // keep the chain alive
    return;
  }

  __shared__ float n_l[S_SLOTS];     // ||t_s||^2, tracked incrementally
  __shared__ float rew[B_ITEMS];
  __shared__ float gdiag[B_ITEMS];   // ||c_i||^2
  __shared__ u64 partials[4];
  __shared__ float sh_gnext;         // G[i][i+1] staged by thread i+1
  __shared__ u32 dslot[B_ITEMS];
  __shared__ float dlr[B_ITEMS];
  __shared__ int sh_state[2];

  const int t = threadIdx.x;          // 0..255
  const int lane = t & 63, wave = t >> 6;

  for (int s = t; s < S_SLOTS; s += 256) n_l[s] = n_g[s];
  rew[t] = rewards[t];
  gdiag[t] = Gb[(size_t)t * B_ITEMS + t];
  if (t == 0) { sh_state[0] = state[0]; sh_state[1] = state[1]; }
  __syncthreads();

  int num = sh_state[0], ptr = sh_state[1];
  const int limit = min(num + B_ITEMS, S_SLOTS);
  const int s0 = t << 4;
  const bool active = s0 < limit;

  float4 c[4];
  if (active) {
    c[0] = *(const float4*)(Q + s0 + 0);
    c[1] = *(const float4*)(Q + s0 + 4);
    c[2] = *(const float4*)(Q + s0 + 8);
    c[3] = *(const float4*)(Q + s0 + 12);
  }
  float gv = Gb[t];                   // Gb row 0
  int slot_prev = -1; float nnew_prev = 0.f;

  for (int i = 0; i < B_ITEMS; i++) {
    // ---- step start: all decision-independent work ----
    float4 cn[4]; float gvnext = 0.f;
    if (i + 1 < B_ITEMS) {
      if (active) {
        const float* qrow = Q + (size_t)(i + 1) * S_SLOTS + s0;
        cn[0] = *(const float4*)(qrow + 0);
        cn[1] = *(const float4*)(qrow + 4);
        cn[2] = *(const float4*)(qrow + 8);
        cn[3] = *(const float4*)(qrow + 12);
      }
      gvnext = Gb[(size_t)(i + 1) * B_ITEMS + t];
    }
    if (t == i + 1) sh_gnext = gv;                  // G[i][i+1]
    if (t == 0 && slot_prev >= 0) n_l[slot_prev] = nnew_prev;  // deferred write

    // ---- phase A: 16-slot compare + wave argmin ----
    const float gi = gdiag[i];
    u64 best = ~0ull;
    if (active) {
#define KEYC(vec, comp, idx) { const int ss = s0 + idx; \
    if (ss < num) { const float d2 = fmaxf(vec.comp + gi, 0.f); \
      const u64 key = ((u64)__float_as_uint(d2) << 32) | (u32)ss; \
      if (key < best) best = key; } }
      KEYC(c[0], x, 0)  KEYC(c[0], y, 1)  KEYC(c[0], z, 2)  KEYC(c[0], w, 3)
      KEYC(c[1], x, 4)  KEYC(c[1], y, 5)  KEYC(c[1], z, 6)  KEYC(c[1], w, 7)
      KEYC(c[2], x, 8)  KEYC(c[2], y, 9)  KEYC(c[2], z, 10) KEYC(c[2], w, 11)
      KEYC(c[3], x, 12) KEYC(c[3], y, 13) KEYC(c[3], z, 14) KEYC(c[3], w, 15)
#undef KEYC
    }
#pragma unroll
    for (int o = 32; o; o >>= 1) {
      const u64 v = __shfl_down(best, o, 64);
      if (v < best) best = v;
    }
    if (lane == 0) partials[wave] = best;
    __syncthreads();

    // ---- phase B: ALL threads compute the decision redundantly ----
    u64 bk = partials[0];
    if (partials[1] < bk) bk = partials[1];
    if (partials[2] < bk) bk = partials[2];
    if (partials[3] < bk) bk = partials[3];
    const float d2b = __uint_as_float((u32)(bk >> 32));
    const int nslot = (int)(u32)bk;
    const bool upd = (num > 0) && (sqrtf(d2b) < DTHRESH);
    const float lr = __fmul_rn(0.01f, __fadd_rn(1.0f, fabsf(rew[i])));
    const int slot = upd ? nslot : ptr;
    const float n_old = n_l[slot];                  // LDS broadcast
    float n_new;
    if (upd) {
      const float omr = 1.0f - lr;
      const float pcur = 0.5f * (n_old + gi - d2b);
      n_new = omr * omr * n_old + 2.0f * lr * omr * pcur + lr * lr * gi;
    } else {
      n_new = gi;
      num = min(num + 1, S_SLOTS);
      ptr = (ptr + 1) & (S_SLOTS - 1);
    }
    if (t == 0) {
      dslot[i] = (u32)slot | (upd ? 0x80000000u : 0u);
      dlr[i] = lr;
    }

    // ---- phase C: apply mutation to future rows ----
    const float omr = 1.0f - lr;
    if (i + 1 < B_ITEMS) {
      if (t == (slot >> 4)) {       // register fixup for row i+1
        const float gnext = sh_gnext;
        const int kq = (slot >> 2) & 3, kc = slot & 3;
#pragma unroll
        for (int q = 0; q < 4; q++) {
          if (q == kq) {
            float4 vv = cn[q];
            const float q_old = kc == 0 ? vv.x : kc == 1 ? vv.y : kc == 2 ? vv.z : vv.w;
            const float p_old = 0.5f * (n_old - q_old);
            const float p_new = upd ? (omr * p_old + lr * gnext) : gnext;
            const float q_new = n_new - 2.0f * p_new;
            if (kc == 0) vv.x = q_new; else if (kc == 1) vv.y = q_new;
            else if (kc == 2) vv.z = q_new; else vv.w = q_new;
            cn[q] = vv;
          }
        }
      }
      if (t > i + 1) {              // L2 RMW for rows i+2..255
        float* qp = Q + (size_t)t * S_SLOTS + slot;
        float p_new;
        if (upd) {
          const float p_old = 0.5f * (n_old - *qp);
          p_new = omr * p_old + lr * gv;
        } else {
          p_new = gv;
        }
        *qp = n_new - 2.0f * p_new;
      }
    }
    slot_prev = slot; nnew_prev = n_new;
    __syncthreads();                // drains RMW stores before next prefetch use

    if (active && i + 1 < B_ITEMS) {
      c[0] = cn[0]; c[1] = cn[1]; c[2] = cn[2]; c[3] = cn[3];
    }
    gv = gvnext;
  }

  if (t == 0) { state[0] = num; state[1] = ptr; }
  decs[t] = ((u64)__float_as_uint(dlr[t]) << 32) | (u64)dslot[t];
  __syncthreads();                   // ensure all WG0 work precedes flag set
  if (t == 0)
    __hip_atomic_store(scanflag, 1, __ATOMIC_RELEASE, __HIP_MEMORY_SCOPE_AGENT);
}

// ---------------------------------------------------------------------------
// apply: materialize the block's trace mutations. WG j owns slot_j iff step j
// is the LAST step touching it. Composition: t = alpha*t_snap + sum beta_j c_j.
// ---------------------------------------------------------------------------
__global__ __launch_bounds__(256)
void apply_kernel(const float* __restrict__ content,  // block 256 x 1024
                  const u64* __restrict__ decs,       // 256 decisions
                  float* __restrict__ traces,         // = out
                  float* __restrict__ n_g) {
  __shared__ u32 aslot[B_ITEMS];
  __shared__ float alr[B_ITEMS];
  __shared__ float betas[B_ITEMS];
  __shared__ int notowner;
  __shared__ float wsum[4];
  const int t = threadIdx.x, j = blockIdx.x;
  const int lane = t & 63, wave = t >> 6;
  const u64 d = decs[t];
  aslot[t] = (u32)(d & 0xFFFFFFFFull);
  alr[t] = __uint_as_float((u32)(d >> 32));
  if (t == 0) notowner = 0;
  __syncthreads();
  const u32 myslot = aslot[j] & 0x7FFFFFFFu;
  if (t > j && (aslot[t] & 0x7FFFFFFFu) == myslot) notowner = 1;
  __syncthreads();
  if (notowner) return;

  float alpha = 1.f, beta = 0.f;
  for (int k = 0; k < B_ITEMS; k++) {
    const u32 a = aslot[k];
    if ((a & 0x7FFFFFFFu) == myslot) {
      const float lr = alr[k];
      if (a & 0x80000000u) {           // update
        const float om = 1.f - lr;
        alpha *= om; beta *= om;
        if (t == k) beta += lr;
      } else {                         // insert
        alpha = 0.f; beta = (t == k) ? 1.f : 0.f;
      }
    }
  }
  betas[t] = beta;
  __syncthreads();

  float4 v = *(const float4*)(traces + (size_t)myslot * D_SEM + 4 * t);
  v.x *= alpha; v.y *= alpha; v.z *= alpha; v.w *= alpha;
  for (int k = 0; k < B_ITEMS; k++) {
    if ((aslot[k] & 0x7FFFFFFFu) == myslot) {
      const float bk = betas[k];
      const float4 c = *(const float4*)(content + (size_t)k * D_SEM + 4 * t);
      v.x = fmaf(bk, c.x, v.x); v.y = fmaf(bk, c.y, v.y);
      v.z = fmaf(bk, c.z, v.z); v.w = fmaf(bk, c.w, v.w);
    }
  }
  *(float4*)(traces + (size_t)myslot * D_SEM + 4 * t) = v;
  float nn = v.x * v.x + v.y * v.y + v.z * v.z + v.w * v.w;
#pragma unroll
  for (int o = 32; o; o >>= 1) nn += __shfl_down(nn, o, 64);
  if (lane == 0) wsum[wave] = nn;
  __syncthreads();
  if (t == 0) n_g[myslot] = wsum[0] + wsum[1] + wsum[2] + wsum[3];
}

// ---------------------------------------------------------------------------
// finalize: parallel strengths replay. Pass 1: last insert index per slot
// (LDS atomicMax). Pass 2: count updates after the last insert (LDS atomicAdd).
// ---------------------------------------------------------------------------
__global__ __launch_bounds__(256)
void finalize_kernel(const float* __restrict__ strengths0,
                     const u64* __restrict__ decs,
                     const int* __restrict__ state, float* __restrict__ out) {
  __shared__ float str[S_SLOTS];
  __shared__ int lastins[S_SLOTS];
  __shared__ float wsum[4];
  const int t = threadIdx.x, lane = t & 63, wave = t >> 6;
  for (int s = t; s < S_SLOTS; s += 256) lastins[s] = -1;
  __syncthreads();
  for (int k = t; k < N_ITEMS; k += 256) {
    const u32 d = (u32)(decs[k] & 0xFFFFFFFFull);
    if (!(d & 0x80000000u)) atomicMax(&lastins[d & 0x7FFFFFFFu], k);
  }
  __syncthreads();
  for (int s = t; s < S_SLOTS; s += 256)
    str[s] = (lastins[s] >= 0) ? 1.f : strengths0[s];
  __syncthreads();
  for (int k = t; k < N_ITEMS; k += 256) {
    const u32 d = (u32)(decs[k] & 0xFFFFFFFFull);
    if (d & 0x80000000u) {
      const int slot = (int)(d & 0x7FFFFFFFu);
      if (k > lastins[slot]) atomicAdd(&str[slot], 1.f);
    }
  }
  __syncthreads();

  const int num = state[0];
  float* outs = out + (size_t)S_SLOTS * D_SEM;
  float lsum = 0.f;
  for (int s = t; s < S_SLOTS; s += 256) {
    const float v = str[s];
    outs[s] = v;
    if (s < num) lsum += v;
  }
#pragma unroll
  for (int o = 32; o; o >>= 1) lsum += __shfl_down(lsum, o, 64);
  if (lane == 0) wsum[wave] = lsum;
  __syncthreads();
  if (t == 0) {
    const float total = wsum[0] + wsum[1] + wsum[2] + wsum[3];
    float denom = (float)num;
    if (denom < 1.f) denom = 1.f;
    outs[S_SLOTS + 0] = (float)num;
    outs[S_SLOTS + 1] = (float)N_ITEMS;
    outs[S_SLOTS + 2] = (num > 0) ? (total / denom) : 0.f;
  }
}

// ---------------------------------------------------------------------------
extern "C" void kernel_launch(void* const* d_in, const int* in_sizes, int n_in,
                              void* d_out, int out_size, void* d_ws, size_t ws_size,
                              hipStream_t stream) {
  const float* states  = (const float*)d_in[0];
  const float* rewards = (const float*)d_in[1];
  const float* W       = (const float*)d_in[2];
  const float* bias    = (const float*)d_in[3];
  const float* traces0 = (const float*)d_in[4];
  const float* str0    = (const float*)d_in[5];
  float* out = (float*)d_out;   // traces live here (working + final)

  // ws layout (~24.6 MB): content chunk 16MB | Q 4MB | Gram 4MB | n_g | decs | state | flag
  char* p = (char*)d_ws;
  float* cbuf = (float*)p;                 p += (size_t)CHUNK_ITEMS * D_SEM * 4;
  float* Q    = (float*)p;                 p += (size_t)B_ITEMS * S_SLOTS * 4;
  float* Gb   = (float*)p;                 p += (size_t)CHUNK_BLKS * B_ITEMS * B_ITEMS * 4;
  float* n_g  = (float*)p;                 p += (size_t)S_SLOTS * 4;
  u64*   decs = (u64*)p;                   p += (size_t)N_ITEMS * 8;
  int*   state = (int*)p;                  p += 64;
  int*   scanflag = (int*)p;

  init_kernel<<<S_SLOTS, 256, 0, stream>>>(traces0, out, n_g, state);

  for (int c = 0; c < N_ITEMS / CHUNK_ITEMS; c++) {
    gemm_kernel<<<dim3(CHUNK_ITEMS / 64, D_SEM / 64), 256, 0, stream>>>(
        states + (size_t)c * CHUNK_ITEMS * D_STATE, W, bias, cbuf);
    gram_kernel<<<dim3(4, 4, CHUNK_BLKS), 256, 0, stream>>>(cbuf, Gb);
    for (int bb = 0; bb < CHUNK_BLKS; bb++) {
      const int b = c * CHUNK_BLKS + bb;
      const float* cblk = cbuf + (size_t)bb * B_ITEMS * D_SEM;
      const float* Gblk = Gb + (size_t)bb * B_ITEMS * B_ITEMS;
      pgemm_kernel<<<dim3(4, S_SLOTS / 64), 256, 0, stream>>>(cblk, out, n_g, Q,
                                                              state, scanflag);
      scan_kernel<<<SCAN_GRID, 256, 0, stream>>>(Q, Gblk,
                                                 rewards + (size_t)b * B_ITEMS,
                                                 n_g, state,
                                                 decs + (size_t)b * B_ITEMS,
                                                 scanflag);
      apply_kernel<<<B_ITEMS, 256, 0, stream>>>(cblk, decs + (size_t)b * B_ITEMS,
                                                out, n_g);
    }
  }
  finalize_kernel<<<1, 256, 0, stream>>>(str0, decs, state, out);
}